// Round 7
// baseline (239.113 us; speedup 1.0000x reference)
//
#include <hip/hip_runtime.h>

// FastVolterra1: out[r,:] = irfft(rfft(x[r,:]) * softmax(w1)), D=1024, fp32.
//
// Real-packed: z[n] = x[2n] + i*x[2n+1] (length 512);
//   Z = FFT_512(z);  W[k] = P[k]*Z[k] + i*q[k]*conj(Z[(512-k)%512]);
//   w = IFFT_512(W); out[2n]=Re w[n], out[2n+1]=Im w[n].
// P,q real, precomputed from softmax gate (1/512 norm folded in).
//
// R7: PHASE-ADDITIVITY model (fits all 6 prior rounds within ~15%):
// wall ~= SUM(VALU 50k) + SUM(LDS-pipe 60-98k) + SUM(global-exposure) cyc,
// with ZERO overlap between phases -- same-code waves convoy on the shared
// LDS queue (drain releases all waiters together = re-sync barrier every
// trip), so inter-wave overlap never materializes (R1 8w/SIMD == R4-6
// 4w/SIMD == 81us; LDS cycles varied 61k<->98k with no effect; R5's b64->
// b128 "op halving" was pipe-cycle-NEUTRAL (12 vs 6 cyc/op, m134) so the
// LDS theory was never really tested).
// Fix: deterministic IN-WAVE phase offset. Each wave owns TWO fused pairs
// (P,Q = 4 rows), each with its own LDS buffer; segment order
//   V(P); trip(P); V(Q); trip(Q); V'(P)...
// puts Q's ~170-instr VALU between P's LDS issue and P's first use, so the
// compiler emits counted lgkmcnt(16) (it tracks its own ds ops) and every
// LDS trip hides under the sibling's butterflies. R4 FAILED because it
// aligned phases (storeA,storeB,loadA,loadB under one blanket wait); this
// offsets them. No inline asm needed.
// Canaries: WRITE_SIZE must stay 131072 KB exactly (VGPR ~170-200, spill =
// compromised); VALUBusy should rise 25 -> 40-55% if overlap engages.
//
// FFT body per pair is BIT-IDENTICAL to R5 (absmax unchanged): 3 radix-8
// Stockham stages fwd+inv, float4 LDS = (Ar,Ai,Br,Bi), pad(e)=e+(e>>3),
// 576 float4/buffer. Bank math (8-lane cluster, mod 8) validated R2/R5.
// Wave-local LDS -> NO __syncthreads. 128-thr blocks, 2 waves, LDS
// 2x2x576x16 = 36,864 B -> 4 blocks/CU, 16 resident pairs/CU (unchanged).

#define R2F 0.70710678118654752f

// 8-point DFT, bins in natural order. Forward = e^{-2pi i/8}; INV conjugates.
template <bool INV>
__device__ __forceinline__ void bfly8(float* xr, float* xi)
{
    float t0r = xr[0] + xr[4], t0i = xi[0] + xi[4];
    float t1r = xr[0] - xr[4], t1i = xi[0] - xi[4];
    float t2r = xr[2] + xr[6], t2i = xi[2] + xi[6];
    float t3r = xr[2] - xr[6], t3i = xi[2] - xi[6];
    float e0r = t0r + t2r, e0i = t0i + t2i;
    float e2r = t0r - t2r, e2i = t0i - t2i;
    float e1r, e1i, e3r, e3i;
    if (!INV) { e1r = t1r + t3i; e1i = t1i - t3r; e3r = t1r - t3i; e3i = t1i + t3r; }
    else      { e1r = t1r - t3i; e1i = t1i + t3r; e3r = t1r + t3i; e3i = t1i - t3r; }
    float s0r = xr[1] + xr[5], s0i = xi[1] + xi[5];
    float s1r = xr[1] - xr[5], s1i = xi[1] - xi[5];
    float s2r = xr[3] + xr[7], s2i = xi[3] + xi[7];
    float s3r = xr[3] - xr[7], s3i = xi[3] - xi[7];
    float o0r = s0r + s2r, o0i = s0i + s2i;
    float o2r = s0r - s2r, o2i = s0i - s2i;
    float o1r, o1i, o3r, o3i;
    if (!INV) { o1r = s1r + s3i; o1i = s1i - s3r; o3r = s1r - s3i; o3i = s1i + s3r; }
    else      { o1r = s1r - s3i; o1i = s1i + s3r; o3r = s1r + s3i; o3i = s1i - s3r; }
    float p1r, p1i, p2r, p2i, p3r, p3i;
    if (!INV) {
        p1r = (o1r + o1i) * R2F;  p1i = (o1i - o1r) * R2F;
        p2r = o2i;                p2i = -o2r;
        p3r = (o3i - o3r) * R2F;  p3i = -(o3r + o3i) * R2F;
    } else {
        p1r = (o1r - o1i) * R2F;  p1i = (o1i + o1r) * R2F;
        p2r = -o2i;               p2i = o2r;
        p3r = -(o3r + o3i) * R2F; p3i = (o3r - o3i) * R2F;
    }
    xr[0] = e0r + o0r; xi[0] = e0i + o0i;
    xr[4] = e0r - o0r; xi[4] = e0i - o0i;
    xr[1] = e1r + p1r; xi[1] = e1i + p1i;
    xr[5] = e1r - p1r; xi[5] = e1i - p1i;
    xr[2] = e2r + p2r; xi[2] = e2i + p2i;
    xr[6] = e2r - p2r; xi[6] = e2i - p2i;
    xr[3] = e3r + p3r; xi[3] = e3i + p3i;
    xr[7] = e3r - p3r; xi[7] = e3i - p3i;
}

// Tables store (cos th, sin th), th >= 0. Forward multiplies by e^{-i th}.
template <bool INV>
__device__ __forceinline__ void tw_apply(float* xr, float* xi,
                                         const float* c, const float* s)
{
#pragma unroll
    for (int k = 1; k < 8; ++k) {
        float r, i;
        if (!INV) { r = xr[k] * c[k] + xi[k] * s[k]; i = xi[k] * c[k] - xr[k] * s[k]; }
        else      { r = xr[k] * c[k] - xi[k] * s[k]; i = xi[k] * c[k] + xr[k] * s[k]; }
        xr[k] = r; xi[k] = i;
    }
}

struct PairRegs { float ar[8], ai[8], br[8], bi[8]; };

// One LDS round trip: b128 store at sbase + sstride*k, b128 load at ld0+72k.
// The loads' first USE is the caller's next bfly -> compiler places a
// counted lgkmcnt there; VALU issued between trip() and that bfly overlaps.
__device__ __forceinline__ void trip(float4* buf, int sbase, int sstride,
                                     int ld0, PairRegs& P)
{
#pragma unroll
    for (int k = 0; k < 8; ++k)
        buf[sbase + sstride * k] = make_float4(P.ar[k], P.ai[k], P.br[k], P.bi[k]);
#pragma unroll
    for (int k = 0; k < 8; ++k) {
        float4 v = buf[ld0 + 72 * k];
        P.ar[k] = v.x; P.ai[k] = v.y; P.br[k] = v.z; P.bi[k] = v.w;
    }
}

__device__ __forceinline__ void fwd_stage(PairRegs& P, const float* c, const float* s)
{
    bfly8<false>(P.ar, P.ai); tw_apply<false>(P.ar, P.ai, c, s);
    bfly8<false>(P.br, P.bi); tw_apply<false>(P.br, P.bi, c, s);
}

__device__ __forceinline__ void inv_stage(PairRegs& P, const float* c, const float* s)
{
    bfly8<true>(P.ar, P.ai); tw_apply<true>(P.ar, P.ai, c, s);
    bfly8<true>(P.br, P.bi); tw_apply<true>(P.br, P.bi, c, s);
}

__device__ __forceinline__ void mirror_write(float4* buf, int ld0, const PairRegs& P)
{
#pragma unroll
    for (int k = 0; k < 8; ++k)
        buf[ld0 + 72 * k] = make_float4(P.ar[k], P.ai[k], P.br[k], P.bi[k]);
}

__device__ __forceinline__ void mirror_read(const float4* buf, int t, float4* mv)
{
#pragma unroll
    for (int k = 0; k < 8; ++k) {
        int m = (512 - (t + 64 * k)) & 511;
        mv[k] = buf[m + (m >> 3)];
    }
}

// W = P*Z + i*q*conj(Zm): nr = P*zr + q*Im(Zm), ni = P*zi + q*Re(Zm)
__device__ __forceinline__ void combine(const float4* mv, const float* pqx,
                                        const float* pqy, PairRegs& P)
{
#pragma unroll
    for (int k = 0; k < 8; ++k) {
        float nrA = pqx[k] * P.ar[k] + pqy[k] * mv[k].y;
        float niA = pqx[k] * P.ai[k] + pqy[k] * mv[k].x;
        float nrB = pqx[k] * P.br[k] + pqy[k] * mv[k].w;
        float niB = pqx[k] * P.bi[k] + pqy[k] * mv[k].z;
        P.ar[k] = nrA; P.ai[k] = niA; P.br[k] = nrB; P.bi[k] = niB;
    }
}

__global__ __launch_bounds__(128)
void fv_kernel(const float2* __restrict__ x,
               const float2* __restrict__ pq,    // (P[k], q[k]) k=0..511
               const float2* __restrict__ tw1,   // [(k-1)*64 + t], k=1..7
               const float2* __restrict__ tw8,   // [(k-1)*8 + p],  k=1..7
               float2* __restrict__ out)
{
    __shared__ float4 sb4[2][2][576];            // [wave][pair], pad(e)=e+(e>>3)
    const int tid = threadIdx.x;
    const int w = tid >> 6;      // wave id within block (0..1)
    const int t = tid & 63;      // lane
    float4* bufP = sb4[w][0];
    float4* bufQ = sb4[w][1];
    const size_t rb = ((size_t)blockIdx.x * 8 + (size_t)w * 4) * 512;  // float2 units
    const size_t bPA = rb, bPB = rb + 512, bQA = rb + 1024, bQB = rb + 1536;

    // twiddle + pq register sets (shared by both pairs)
    float c1[8], s1[8], c8[8], s8[8];
#pragma unroll
    for (int k = 1; k < 8; ++k) {
        float2 wv = tw1[(k - 1) * 64 + t];       c1[k] = wv.x; s1[k] = wv.y;
        float2 v  = tw8[(k - 1) * 8 + (t >> 3)]; c8[k] = v.x;  s8[k] = v.y;
    }
    float pqx[8], pqy[8];
#pragma unroll
    for (int k = 0; k < 8; ++k) {
        float2 g = pq[t + 64 * k];
        pqx[k] = g.x; pqy[k] = g.y;
    }

    // padded addresses (float4 units), pad(e)=e+(e>>3):
    const int st1 = 9 * t;                   // + k
    const int ld0 = t + (t >> 3);            // + 72*k  (== pad(t+64k))
    const int st2 = (t & 7) + 72 * (t >> 3); // + 9*k

    PairRegs P, Q;

    // ---- global loads, both pairs (P's first -> vmcnt(16) before P use) ----
#pragma unroll
    for (int k = 0; k < 8; ++k) { float2 v = x[bPA + t + 64 * k]; P.ar[k] = v.x; P.ai[k] = v.y; }
#pragma unroll
    for (int k = 0; k < 8; ++k) { float2 v = x[bPB + t + 64 * k]; P.br[k] = v.x; P.bi[k] = v.y; }
#pragma unroll
    for (int k = 0; k < 8; ++k) { float2 v = x[bQA + t + 64 * k]; Q.ar[k] = v.x; Q.ai[k] = v.y; }
#pragma unroll
    for (int k = 0; k < 8; ++k) { float2 v = x[bQB + t + 64 * k]; Q.br[k] = v.x; Q.bi[k] = v.y; }

    // ---- forward stage 1 (V then trip, P/Q offset) ----
    fwd_stage(P, c1, s1);  trip(bufP, st1, 1, ld0, P);
    fwd_stage(Q, c1, s1);  trip(bufQ, st1, 1, ld0, Q);
    // ---- forward stage 2 ----
    fwd_stage(P, c8, s8);  trip(bufP, st2, 9, ld0, P);
    fwd_stage(Q, c8, s8);  trip(bufQ, st2, 9, ld0, Q);
    // ---- stage 3 + mirror (reads issue, use deferred past sibling VALU) ----
    float4 mvP[8], mvQ[8];
    bfly8<false>(P.ar, P.ai); bfly8<false>(P.br, P.bi);
    mirror_write(bufP, ld0, P); mirror_read(bufP, t, mvP);
    bfly8<false>(Q.ar, Q.ai); bfly8<false>(Q.br, Q.bi);
    mirror_write(bufQ, ld0, Q); mirror_read(bufQ, t, mvQ);
    // ---- combine + inverse stage 1 ----
    combine(mvP, pqx, pqy, P);
    inv_stage(P, c1, s1);  trip(bufP, st1, 1, ld0, P);
    combine(mvQ, pqx, pqy, Q);
    inv_stage(Q, c1, s1);  trip(bufQ, st1, 1, ld0, Q);
    // ---- inverse stage 2 ----
    inv_stage(P, c8, s8);  trip(bufP, st2, 9, ld0, P);
    inv_stage(Q, c8, s8);  trip(bufQ, st2, 9, ld0, Q);
    // ---- final butterflies + stores (Q's VALU overlaps P's stores) ----
    bfly8<true>(P.ar, P.ai); bfly8<true>(P.br, P.bi);
#pragma unroll
    for (int k = 0; k < 8; ++k) out[bPA + t + 64 * k] = make_float2(P.ar[k], P.ai[k]);
#pragma unroll
    for (int k = 0; k < 8; ++k) out[bPB + t + 64 * k] = make_float2(P.br[k], P.bi[k]);
    bfly8<true>(Q.ar, Q.ai); bfly8<true>(Q.br, Q.bi);
#pragma unroll
    for (int k = 0; k < 8; ++k) out[bQA + t + 64 * k] = make_float2(Q.ar[k], Q.ai[k]);
#pragma unroll
    for (int k = 0; k < 8; ++k) out[bQB + t + 64 * k] = make_float2(Q.br[k], Q.bi[k]);
}

// Build softmax gate -> (P,q) table and twiddle tables, all in d_ws.
__global__ void gate_kernel(const float* __restrict__ w1,
                            float2* __restrict__ pq,
                            float2* __restrict__ tw1,
                            float2* __restrict__ tw8)
{
    __shared__ float red[1024];
    __shared__ float ex[513];
    const int t = threadIdx.x;  // 1024 threads

    float v = (t < 513) ? w1[t] : -1e30f;
    red[t] = v;
    __syncthreads();
    for (int off = 512; off > 0; off >>= 1) {
        if (t < off) red[t] = fmaxf(red[t], red[t + off]);
        __syncthreads();
    }
    float M = red[0];
    __syncthreads();

    float e = (t < 513) ? expf(w1[t] - M) : 0.0f;
    if (t < 513) ex[t] = e;
    red[t] = e;
    __syncthreads();
    for (int off = 512; off > 0; off >>= 1) {
        if (t < off) red[t] += red[t + off];
        __syncthreads();
    }
    float inv = 1.0f / red[0];
    __syncthreads();

    if (t < 512) {
        float ga = ex[t] * inv;
        float gb = ex[512 - t] * inv;
        float gp = ga + gb, gm = ga - gb;
        float th = (float)t * 6.13592315154256492e-03f;  // pi/512 * t = 2*pi*t/1024
        float sn, cs;
        __sincosf(th, &sn, &cs);
        float P = 0.5f * (gp - gm * sn) * (1.0f / 512.0f);
        float q = 0.5f * (gm * cs) * (1.0f / 512.0f);
        pq[t] = make_float2(P, q);
    }
    if (t < 448) {
        int k = (t >> 6) + 1;
        int j = t & 63;
        float th = (float)(j * k) * 1.22718463151036952e-02f;  // 2*pi/512
        float sn, cs;
        sincosf(th, &sn, &cs);
        tw1[t] = make_float2(cs, sn);
    }
    if (t < 56) {
        int k = (t >> 3) + 1;
        int p = t & 7;
        float th = (float)(p * k) * 9.81747704246810387e-02f;  // 2*pi/64
        float sn, cs;
        sincosf(th, &sn, &cs);
        tw8[t] = make_float2(cs, sn);
    }
}

extern "C" void kernel_launch(void* const* d_in, const int* in_sizes, int n_in,
                              void* d_out, int out_size, void* d_ws, size_t ws_size,
                              hipStream_t stream)
{
    (void)n_in; (void)out_size; (void)ws_size;
    const float2* hidden = (const float2*)d_in[0];   // [32768 rows, 512 float2]
    const float*  w1     = (const float*)d_in[1];    // [513]
    float2* out = (float2*)d_out;

    float2* pq  = (float2*)d_ws;          // 512 float2
    float2* tw1 = pq + 512;               // 448 float2
    float2* tw8 = tw1 + 448;              // 56  float2

    gate_kernel<<<1, 1024, 0, stream>>>(w1, pq, tw1, tw8);

    const int rows   = in_sizes[0] / 1024;   // 32768
    const int blocks = rows / 8;             // 4096 (8 rows/block: 2 waves x 2 pairs)
    fv_kernel<<<blocks, 128, 0, stream>>>(hidden, pq, tw1, tw8, out);
}

// Round 8
// 238.343 us; speedup vs baseline: 1.0032x; 1.0032x over previous
//
#include <hip/hip_runtime.h>

// FastVolterra1: out[r,:] = irfft(rfft(x[r,:]) * softmax(w1)), D=1024, fp32.
//
// Real-packed: z[n] = x[2n] + i*x[2n+1] (length 512);
//   Z = FFT_512(z);  W[k] = P[k]*Z[k] + i*q[k]*conj(Z[(512-k)%512]);
//   w = IFFT_512(W); out[2n]=Re w[n], out[2n+1]=Im w[n].
// P,q real, precomputed from softmax gate (1/512 norm folded in).
//
// R8: R7's software pipeline, PINNED. R7's post-mortem: VGPR=88 proves the
// machine scheduler collapsed the P/Q interleave (two co-live pairs need
// ~150 regs); pressure-minimizing scheduling is anti-pipelining, so the
// source-order V(P);trip(P);V(Q);trip(Q) never reached the hardware and
// VALUBusy stayed 25%. Fix:
//  (a) __builtin_amdgcn_sched_barrier(0) fence between every segment --
//      no instruction may cross, so the emitted order interleaves pairs;
//      SIInsertWaitcnts then emits counted lgkmcnt(16) before P's use
//      (in-order lgkm: Q's 16 DS ops stay outstanding), hiding each LDS
//      trip + the gload wait under the sibling's ~350cyc VALU segment.
//      (r141 showed SB(0) hurts when compiler scheduling is GOOD; here the
//      compiler's pressure-driven schedule is precisely the thing to defeat.)
//  (b) __launch_bounds__(128,1): allow up to 256 VGPR. Occupancy is
//      LDS-capped at 4 blocks/CU = 2 waves/SIMD anyway (36,864 B/block),
//      so VGPR 150-210 costs nothing -- removes the allocator's incentive
//      to re-serialize.
// Canary: VGPR 88 -> 140-210 with WRITE_SIZE == 131072 KB exactly (no
// scratch). If order pinned + VGPR up and fv still >=75us: declare floor.
//
// FFT body per pair BIT-IDENTICAL to R5-R7 (absmax unchanged): 3 radix-8
// Stockham stages fwd+inv, float4 LDS = (Ar,Ai,Br,Bi), pad(e)=e+(e>>3),
// 576 float4/buffer, bank math validated (R2/R5, 8-lane-cluster mod-8).
// Wave-local LDS -> NO __syncthreads.

#define R2F 0.70710678118654752f
#define SFENCE() __builtin_amdgcn_sched_barrier(0)

// 8-point DFT, bins in natural order. Forward = e^{-2pi i/8}; INV conjugates.
template <bool INV>
__device__ __forceinline__ void bfly8(float* xr, float* xi)
{
    float t0r = xr[0] + xr[4], t0i = xi[0] + xi[4];
    float t1r = xr[0] - xr[4], t1i = xi[0] - xi[4];
    float t2r = xr[2] + xr[6], t2i = xi[2] + xi[6];
    float t3r = xr[2] - xr[6], t3i = xi[2] - xi[6];
    float e0r = t0r + t2r, e0i = t0i + t2i;
    float e2r = t0r - t2r, e2i = t0i - t2i;
    float e1r, e1i, e3r, e3i;
    if (!INV) { e1r = t1r + t3i; e1i = t1i - t3r; e3r = t1r - t3i; e3i = t1i + t3r; }
    else      { e1r = t1r - t3i; e1i = t1i + t3r; e3r = t1r + t3i; e3i = t1i - t3r; }
    float s0r = xr[1] + xr[5], s0i = xi[1] + xi[5];
    float s1r = xr[1] - xr[5], s1i = xi[1] - xi[5];
    float s2r = xr[3] + xr[7], s2i = xi[3] + xi[7];
    float s3r = xr[3] - xr[7], s3i = xi[3] - xi[7];
    float o0r = s0r + s2r, o0i = s0i + s2i;
    float o2r = s0r - s2r, o2i = s0i - s2i;
    float o1r, o1i, o3r, o3i;
    if (!INV) { o1r = s1r + s3i; o1i = s1i - s3r; o3r = s1r - s3i; o3i = s1i + s3r; }
    else      { o1r = s1r - s3i; o1i = s1i + s3r; o3r = s1r + s3i; o3i = s1i - s3r; }
    float p1r, p1i, p2r, p2i, p3r, p3i;
    if (!INV) {
        p1r = (o1r + o1i) * R2F;  p1i = (o1i - o1r) * R2F;
        p2r = o2i;                p2i = -o2r;
        p3r = (o3i - o3r) * R2F;  p3i = -(o3r + o3i) * R2F;
    } else {
        p1r = (o1r - o1i) * R2F;  p1i = (o1i + o1r) * R2F;
        p2r = -o2i;               p2i = o2r;
        p3r = -(o3r + o3i) * R2F; p3i = (o3r - o3i) * R2F;
    }
    xr[0] = e0r + o0r; xi[0] = e0i + o0i;
    xr[4] = e0r - o0r; xi[4] = e0i - o0i;
    xr[1] = e1r + p1r; xi[1] = e1i + p1i;
    xr[5] = e1r - p1r; xi[5] = e1i - p1i;
    xr[2] = e2r + p2r; xi[2] = e2i + p2i;
    xr[6] = e2r - p2r; xi[6] = e2i - p2i;
    xr[3] = e3r + p3r; xi[3] = e3i + p3i;
    xr[7] = e3r - p3r; xi[7] = e3i - p3i;
}

// Tables store (cos th, sin th), th >= 0. Forward multiplies by e^{-i th}.
template <bool INV>
__device__ __forceinline__ void tw_apply(float* xr, float* xi,
                                         const float* c, const float* s)
{
#pragma unroll
    for (int k = 1; k < 8; ++k) {
        float r, i;
        if (!INV) { r = xr[k] * c[k] + xi[k] * s[k]; i = xi[k] * c[k] - xr[k] * s[k]; }
        else      { r = xr[k] * c[k] - xi[k] * s[k]; i = xi[k] * c[k] + xr[k] * s[k]; }
        xr[k] = r; xi[k] = i;
    }
}

struct PairRegs { float ar[8], ai[8], br[8], bi[8]; };

// One LDS round trip: b128 store at sbase + sstride*k, b128 load at ld0+72k.
__device__ __forceinline__ void trip(float4* buf, int sbase, int sstride,
                                     int ld0, PairRegs& P)
{
#pragma unroll
    for (int k = 0; k < 8; ++k)
        buf[sbase + sstride * k] = make_float4(P.ar[k], P.ai[k], P.br[k], P.bi[k]);
#pragma unroll
    for (int k = 0; k < 8; ++k) {
        float4 v = buf[ld0 + 72 * k];
        P.ar[k] = v.x; P.ai[k] = v.y; P.br[k] = v.z; P.bi[k] = v.w;
    }
}

__device__ __forceinline__ void fwd_stage(PairRegs& P, const float* c, const float* s)
{
    bfly8<false>(P.ar, P.ai); tw_apply<false>(P.ar, P.ai, c, s);
    bfly8<false>(P.br, P.bi); tw_apply<false>(P.br, P.bi, c, s);
}

__device__ __forceinline__ void inv_stage(PairRegs& P, const float* c, const float* s)
{
    bfly8<true>(P.ar, P.ai); tw_apply<true>(P.ar, P.ai, c, s);
    bfly8<true>(P.br, P.bi); tw_apply<true>(P.br, P.bi, c, s);
}

__device__ __forceinline__ void mirror_write(float4* buf, int ld0, const PairRegs& P)
{
#pragma unroll
    for (int k = 0; k < 8; ++k)
        buf[ld0 + 72 * k] = make_float4(P.ar[k], P.ai[k], P.br[k], P.bi[k]);
}

__device__ __forceinline__ void mirror_read(const float4* buf, int t, float4* mv)
{
#pragma unroll
    for (int k = 0; k < 8; ++k) {
        int m = (512 - (t + 64 * k)) & 511;
        mv[k] = buf[m + (m >> 3)];
    }
}

// W = P*Z + i*q*conj(Zm): nr = P*zr + q*Im(Zm), ni = P*zi + q*Re(Zm)
__device__ __forceinline__ void combine(const float4* mv, const float* pqx,
                                        const float* pqy, PairRegs& P)
{
#pragma unroll
    for (int k = 0; k < 8; ++k) {
        float nrA = pqx[k] * P.ar[k] + pqy[k] * mv[k].y;
        float niA = pqx[k] * P.ai[k] + pqy[k] * mv[k].x;
        float nrB = pqx[k] * P.br[k] + pqy[k] * mv[k].w;
        float niB = pqx[k] * P.bi[k] + pqy[k] * mv[k].z;
        P.ar[k] = nrA; P.ai[k] = niA; P.br[k] = nrB; P.bi[k] = niB;
    }
}

__global__ __launch_bounds__(128, 1)
void fv_kernel(const float2* __restrict__ x,
               const float2* __restrict__ pq,    // (P[k], q[k]) k=0..511
               const float2* __restrict__ tw1,   // [(k-1)*64 + t], k=1..7
               const float2* __restrict__ tw8,   // [(k-1)*8 + p],  k=1..7
               float2* __restrict__ out)
{
    __shared__ float4 sb4[2][2][576];            // [wave][pair], pad(e)=e+(e>>3)
    const int tid = threadIdx.x;
    const int w = tid >> 6;      // wave id within block (0..1)
    const int t = tid & 63;      // lane
    float4* bufP = sb4[w][0];
    float4* bufQ = sb4[w][1];
    const size_t rb = ((size_t)blockIdx.x * 8 + (size_t)w * 4) * 512;  // float2 units
    const size_t bPA = rb, bPB = rb + 512, bQA = rb + 1024, bQB = rb + 1536;

    // twiddle + pq register sets (shared by both pairs)
    float c1[8], s1[8], c8[8], s8[8];
#pragma unroll
    for (int k = 1; k < 8; ++k) {
        float2 wv = tw1[(k - 1) * 64 + t];       c1[k] = wv.x; s1[k] = wv.y;
        float2 v  = tw8[(k - 1) * 8 + (t >> 3)]; c8[k] = v.x;  s8[k] = v.y;
    }
    float pqx[8], pqy[8];
#pragma unroll
    for (int k = 0; k < 8; ++k) {
        float2 g = pq[t + 64 * k];
        pqx[k] = g.x; pqy[k] = g.y;
    }

    // padded addresses (float4 units), pad(e)=e+(e>>3):
    const int st1 = 9 * t;                   // + k
    const int ld0 = t + (t >> 3);            // + 72*k  (== pad(t+64k))
    const int st2 = (t & 7) + 72 * (t >> 3); // + 9*k

    PairRegs P, Q;

    // ---- global loads, both pairs (P first: counted vmcnt before P use) ----
#pragma unroll
    for (int k = 0; k < 8; ++k) { float2 v = x[bPA + t + 64 * k]; P.ar[k] = v.x; P.ai[k] = v.y; }
#pragma unroll
    for (int k = 0; k < 8; ++k) { float2 v = x[bPB + t + 64 * k]; P.br[k] = v.x; P.bi[k] = v.y; }
#pragma unroll
    for (int k = 0; k < 8; ++k) { float2 v = x[bQA + t + 64 * k]; Q.ar[k] = v.x; Q.ai[k] = v.y; }
#pragma unroll
    for (int k = 0; k < 8; ++k) { float2 v = x[bQB + t + 64 * k]; Q.br[k] = v.x; Q.bi[k] = v.y; }
    SFENCE();

    // ---- forward stage 1, pinned P/Q offset ----
    fwd_stage(P, c1, s1);            SFENCE();
    trip(bufP, st1, 1, ld0, P);      SFENCE();
    fwd_stage(Q, c1, s1);            SFENCE();
    trip(bufQ, st1, 1, ld0, Q);      SFENCE();
    // ---- forward stage 2 ----
    fwd_stage(P, c8, s8);            SFENCE();
    trip(bufP, st2, 9, ld0, P);      SFENCE();
    fwd_stage(Q, c8, s8);            SFENCE();
    trip(bufQ, st2, 9, ld0, Q);      SFENCE();
    // ---- stage 3 + mirror (reads issue; use deferred past sibling VALU) ----
    float4 mvP[8], mvQ[8];
    bfly8<false>(P.ar, P.ai); bfly8<false>(P.br, P.bi);   SFENCE();
    mirror_write(bufP, ld0, P); mirror_read(bufP, t, mvP); SFENCE();
    bfly8<false>(Q.ar, Q.ai); bfly8<false>(Q.br, Q.bi);   SFENCE();
    mirror_write(bufQ, ld0, Q); mirror_read(bufQ, t, mvQ); SFENCE();
    // ---- combine + inverse stage 1 ----
    combine(mvP, pqx, pqy, P);
    inv_stage(P, c1, s1);            SFENCE();
    trip(bufP, st1, 1, ld0, P);      SFENCE();
    combine(mvQ, pqx, pqy, Q);
    inv_stage(Q, c1, s1);            SFENCE();
    trip(bufQ, st1, 1, ld0, Q);      SFENCE();
    // ---- inverse stage 2 ----
    inv_stage(P, c8, s8);            SFENCE();
    trip(bufP, st2, 9, ld0, P);      SFENCE();
    inv_stage(Q, c8, s8);            SFENCE();
    trip(bufQ, st2, 9, ld0, Q);      SFENCE();
    // ---- final butterflies + stores (Q's VALU overlaps P's stores) ----
    bfly8<true>(P.ar, P.ai); bfly8<true>(P.br, P.bi);     SFENCE();
#pragma unroll
    for (int k = 0; k < 8; ++k) out[bPA + t + 64 * k] = make_float2(P.ar[k], P.ai[k]);
#pragma unroll
    for (int k = 0; k < 8; ++k) out[bPB + t + 64 * k] = make_float2(P.br[k], P.bi[k]);
    SFENCE();
    bfly8<true>(Q.ar, Q.ai); bfly8<true>(Q.br, Q.bi);     SFENCE();
#pragma unroll
    for (int k = 0; k < 8; ++k) out[bQA + t + 64 * k] = make_float2(Q.ar[k], Q.ai[k]);
#pragma unroll
    for (int k = 0; k < 8; ++k) out[bQB + t + 64 * k] = make_float2(Q.br[k], Q.bi[k]);
}

// Build softmax gate -> (P,q) table and twiddle tables, all in d_ws.
__global__ void gate_kernel(const float* __restrict__ w1,
                            float2* __restrict__ pq,
                            float2* __restrict__ tw1,
                            float2* __restrict__ tw8)
{
    __shared__ float red[1024];
    __shared__ float ex[513];
    const int t = threadIdx.x;  // 1024 threads

    float v = (t < 513) ? w1[t] : -1e30f;
    red[t] = v;
    __syncthreads();
    for (int off = 512; off > 0; off >>= 1) {
        if (t < off) red[t] = fmaxf(red[t], red[t + off]);
        __syncthreads();
    }
    float M = red[0];
    __syncthreads();

    float e = (t < 513) ? expf(w1[t] - M) : 0.0f;
    if (t < 513) ex[t] = e;
    red[t] = e;
    __syncthreads();
    for (int off = 512; off > 0; off >>= 1) {
        if (t < off) red[t] += red[t + off];
        __syncthreads();
    }
    float inv = 1.0f / red[0];
    __syncthreads();

    if (t < 512) {
        float ga = ex[t] * inv;
        float gb = ex[512 - t] * inv;
        float gp = ga + gb, gm = ga - gb;
        float th = (float)t * 6.13592315154256492e-03f;  // pi/512 * t = 2*pi*t/1024
        float sn, cs;
        __sincosf(th, &sn, &cs);
        float P = 0.5f * (gp - gm * sn) * (1.0f / 512.0f);
        float q = 0.5f * (gm * cs) * (1.0f / 512.0f);
        pq[t] = make_float2(P, q);
    }
    if (t < 448) {
        int k = (t >> 6) + 1;
        int j = t & 63;
        float th = (float)(j * k) * 1.22718463151036952e-02f;  // 2*pi/512
        float sn, cs;
        sincosf(th, &sn, &cs);
        tw1[t] = make_float2(cs, sn);
    }
    if (t < 56) {
        int k = (t >> 3) + 1;
        int p = t & 7;
        float th = (float)(p * k) * 9.81747704246810387e-02f;  // 2*pi/64
        float sn, cs;
        sincosf(th, &sn, &cs);
        tw8[t] = make_float2(cs, sn);
    }
}

extern "C" void kernel_launch(void* const* d_in, const int* in_sizes, int n_in,
                              void* d_out, int out_size, void* d_ws, size_t ws_size,
                              hipStream_t stream)
{
    (void)n_in; (void)out_size; (void)ws_size;
    const float2* hidden = (const float2*)d_in[0];   // [32768 rows, 512 float2]
    const float*  w1     = (const float*)d_in[1];    // [513]
    float2* out = (float2*)d_out;

    float2* pq  = (float2*)d_ws;          // 512 float2
    float2* tw1 = pq + 512;               // 448 float2
    float2* tw8 = tw1 + 448;              // 56  float2

    gate_kernel<<<1, 1024, 0, stream>>>(w1, pq, tw1, tw8);

    const int rows   = in_sizes[0] / 1024;   // 32768
    const int blocks = rows / 8;             // 4096 (8 rows/block: 2 waves x 2 pairs)
    fv_kernel<<<blocks, 128, 0, stream>>>(hidden, pq, tw1, tw8, out);
}